// Round 4
// baseline (255.141 us; speedup 1.0000x reference)
//
#include <hip/hip_runtime.h>

// out[i] = image[i*3 + 0] * w[i*16 + 15], i in [0, 4096*4096)
//
// Lane-dense mapping: idx = blockBase + k*256 + tid, k=0..3.
//   w:   lane stride 64B -> 2 lanes per 128B line merge in the coalescer;
//        each wave instruction covers a dense aligned 4KB of w (80% of traffic).
//   img: scalar ch-0 loads, lane stride 12B -> ~10 lanes/line merge; every
//        sector of image is needed regardless, HBM bytes unchanged.
//   out: dense scalar stores, 256B contiguous per wave instruction.
// Traffic floor: 201MB (img) + 1074MB (w sectors) + 67MB (out) = 1.342 GB.

__global__ __launch_bounds__(256) void MyLayer_kernel(
    const float* __restrict__ img,
    const float* __restrict__ w,
    float*       __restrict__ out)
{
    const int    tid       = threadIdx.x;
    const size_t blockBase = (size_t)blockIdx.x * (256 * 4);

#pragma unroll
    for (int k = 0; k < 4; ++k) {
        const size_t idx = blockBase + (size_t)k * 256 + tid;
        out[idx] = img[idx * 3] * w[idx * 16 + 15];
    }
}

extern "C" void kernel_launch(void* const* d_in, const int* in_sizes, int n_in,
                              void* d_out, int out_size, void* d_ws, size_t ws_size,
                              hipStream_t stream)
{
    const float* image = (const float*)d_in[0];  // (4096,4096,3) f32
    const float* w     = (const float*)d_in[1];  // (4096,4096,16) f32
    float*       out   = (float*)d_out;          // (4096,4096) f32

    const int n = 4096 * 4096;
    const int threads = 256;
    const int blocks  = n / 4 / threads;         // 16384, exact

    MyLayer_kernel<<<blocks, threads, 0, stream>>>(image, w, out);
}

// Round 5
// 246.845 us; speedup vs baseline: 1.0336x; 1.0336x over previous
//
#include <hip/hip_runtime.h>

// out[i] = image[i*3 + 0] * w[i*16 + 15], i in [0, 4096*4096)
//
// R1 structure (best so far: 231us) + lane-dense w gather via LDS:
//   img: 3x float4 contiguous loads per thread (4 outputs/thread) — issued
//        BEFORE the barrier so they overlap the w-load latency.
//   w:   lane-dense load j = k*256 + tid (64B lane stride -> 2 lanes per
//        128B line merge in the coalescer; halves L2 requests on the
//        1.07GB stream), redistributed through 4KB LDS.
//   out: float4 stores, thread owns 4 consecutive outputs.
// Traffic floor: 201MB (img) + 1074MB (w sectors) + 67MB (out) = 1.342 GB.

typedef float f32x4 __attribute__((ext_vector_type(4)));

__global__ __launch_bounds__(256) void MyLayer_kernel(
    const f32x4* __restrict__ img4,
    const float* __restrict__ w,
    f32x4*       __restrict__ out4)
{
    __shared__ float wl[1024];                       // one w value per output
    const int    tid       = threadIdx.x;
    const size_t blockBase = (size_t)blockIdx.x * 1024;   // outputs per block

    // lane-dense w loads: consecutive lanes -> consecutive needed dwords
    // (addr stride 64B across lanes; writes to LDS stride-4B, conflict-free)
#pragma unroll
    for (int k = 0; k < 4; ++k) {
        const size_t j = blockBase + (size_t)(k * 256 + tid);
        wl[k * 256 + tid] = w[j * 16 + 15];
    }

    // image loads for this thread's 4 outputs (overlap with w latency)
    const size_t t  = blockBase / 4 + tid;           // float4-output index
    const size_t ib = t * 3;
    const f32x4 a = img4[ib + 0];
    const f32x4 b = img4[ib + 1];
    const f32x4 c = img4[ib + 2];

    __syncthreads();

    // ds_read_b128, 16B lane stride — standard conflict-free pattern
    const f32x4 wv = *reinterpret_cast<const f32x4*>(&wl[4 * tid]);

    f32x4 o;
    o.x = a.x * wv.x;   // (4T+0)*3
    o.y = a.w * wv.y;   // (4T+1)*3
    o.z = b.z * wv.z;   // (4T+2)*3
    o.w = c.y * wv.w;   // (4T+3)*3
    out4[t] = o;
}

extern "C" void kernel_launch(void* const* d_in, const int* in_sizes, int n_in,
                              void* d_out, int out_size, void* d_ws, size_t ws_size,
                              hipStream_t stream)
{
    const float* image = (const float*)d_in[0];  // (4096,4096,3) f32
    const float* w     = (const float*)d_in[1];  // (4096,4096,16) f32
    float*       out   = (float*)d_out;          // (4096,4096) f32

    const int n = 4096 * 4096;
    const int threads = 256;
    const int blocks  = n / 4 / threads;         // 16384, exact

    MyLayer_kernel<<<blocks, threads, 0, stream>>>(
        (const f32x4*)image, w, (f32x4*)out);
}